// Round 9
// baseline (1049.705 us; speedup 1.0000x reference)
//
#include <hip/hip_runtime.h>

#define NROWS 100000
#define DDIM 256
#define HDIM 64
#define RPB 256            // rows per block in k_scores (4 waves, 1 row/thread)
#define DCHUNK 32
#define NCHUNK (DDIM / DCHUNK)

__device__ __forceinline__ float fast_tanh(float x) {
  // tanh(x) = 1 - 2/(exp(2x)+1); exact limits at +-inf, ~1ulp elsewhere
  float e = __expf(2.0f * x);
  return 1.0f - 2.0f * __builtin_amdgcn_rcpf(e + 1.0f);
}

// order-preserving float<->uint map for atomicMax over signed floats
__device__ __forceinline__ unsigned enc_key(float f) {
  unsigned b = __float_as_uint(f);
  return (b & 0x80000000u) ? ~b : (b | 0x80000000u);
}
__device__ __forceinline__ float dec_key(unsigned k) {
  unsigned b = (k & 0x80000000u) ? (k & 0x7fffffffu) : ~k;
  return __uint_as_float(b);
}

// cells[0..2] = branch max keys (memset 0 == identity), cells[3..5] = float sums
__global__ __launch_bounds__(256, 1)   // (256,1): allow full VGPR budget, NO acc spill
void k_scores(const float* __restrict__ ZT, const float* __restrict__ ZC,
              const float* __restrict__ ZF,
              const float* __restrict__ WT, const float* __restrict__ bT,
              const float* __restrict__ WC, const float* __restrict__ bC,
              const float* __restrict__ WF, const float* __restrict__ bF,
              const float* __restrict__ q, float* __restrict__ scores,
              unsigned* __restrict__ cells) {
  const int br = blockIdx.y;
  const float* __restrict__ Z = (br == 0) ? ZT : (br == 1) ? ZC : ZF;
  const float* __restrict__ W = (br == 0) ? WT : (br == 1) ? WC : WF;
  const float* __restrict__ B = (br == 0) ? bT : (br == 1) ? bC : bF;

  const int tid = threadIdx.x;
  const int myrow = blockIdx.x * RPB + tid;
  const int row = (myrow < NROWS) ? myrow : (NROWS - 1);   // clamp: loads stay valid
  const float* __restrict__ zp = Z + (size_t)row * DDIM;

  float acc[HDIM];
#pragma unroll
  for (int j = 0; j < HDIM; ++j) acc[j] = B[j];            // uniform -> s_load

#pragma unroll 1
  for (int c = 0; c < NCHUNK; ++c) {
    // my row's chunk: 8 consecutive float4 = one full 128B line per thread
    float zr[DCHUNK];
#pragma unroll
    for (int k = 0; k < DCHUNK / 4; ++k)
      *(float4*)(&zr[k * 4]) = *(const float4*)(zp + c * DCHUNK + k * 4);

    // W row is wave-uniform -> s_load + SGPR operand in v_fmac_f32
#pragma unroll
    for (int j = 0; j < HDIM; ++j) {
      const float* __restrict__ Wp = W + j * DDIM + c * DCHUNK;
#pragma unroll
      for (int dd = 0; dd < DCHUNK; ++dd)
        acc[j] = fmaf(Wp[dd], zr[dd], acc[j]);
    }
  }

  float s = 0.f;
#pragma unroll
  for (int j = 0; j < HDIM; ++j) s += q[j] * fast_tanh(acc[j]);

  if (myrow < NROWS) scores[(size_t)br * NROWS + myrow] = s;

  // fused global max: wave reduce -> block reduce -> one atomic per block
  float m = (myrow < NROWS) ? s : -3.4e38f;
#pragma unroll
  for (int off = 32; off > 0; off >>= 1) m = fmaxf(m, __shfl_down(m, off, 64));
  __shared__ float wmax[4];
  if ((tid & 63) == 0) wmax[tid >> 6] = m;
  __syncthreads();
  if (tid == 0) {
    m = fmaxf(fmaxf(wmax[0], wmax[1]), fmaxf(wmax[2], wmax[3]));
    atomicMax(&cells[br], enc_key(m));
  }
}

__global__ __launch_bounds__(256)
void k_redsum(const float* __restrict__ scores, const unsigned* __restrict__ cells,
              float* __restrict__ sums) {
  const int br = blockIdx.y;
  const float mx = dec_key(cells[br]);
  const float* __restrict__ s = scores + (size_t)br * NROWS;
  float a = 0.f;
  for (int i = blockIdx.x * blockDim.x + threadIdx.x; i < NROWS;
       i += gridDim.x * blockDim.x)
    a += __expf(s[i] - mx);
#pragma unroll
  for (int off = 32; off > 0; off >>= 1) a += __shfl_down(a, off, 64);
  __shared__ float wsum[4];
  if ((threadIdx.x & 63) == 0) wsum[threadIdx.x >> 6] = a;
  __syncthreads();
  if (threadIdx.x == 0)
    atomicAdd(&sums[br], wsum[0] + wsum[1] + wsum[2] + wsum[3]);
}

__global__ __launch_bounds__(256)
void k_out(const float* __restrict__ ZT, const float* __restrict__ ZC,
           const float* __restrict__ ZF,
           const float* __restrict__ scores, const unsigned* __restrict__ cells,
           const float* __restrict__ sums, float* __restrict__ out) {
  const float mT = dec_key(cells[0]);
  const float mC = dec_key(cells[1]);
  const float mF = dec_key(cells[2]);
  const float rT = 1.0f / sums[0];
  const float rC = 1.0f / sums[1];
  const float rF = 1.0f / sums[2];

  const long long total4 = (long long)NROWS * (DDIM / 4);
  for (long long g = (long long)blockIdx.x * 256 + threadIdx.x; g < total4;
       g += (long long)gridDim.x * 256) {
    const int row = (int)(g >> 6);   // one wave covers exactly one row
    const float aT = __expf(scores[row] - mT) * rT;
    const float aC = __expf(scores[NROWS + row] - mC) * rC;
    const float aF = __expf(scores[2 * NROWS + row] - mF) * rF;

    const size_t off = (size_t)g;
    const float4 zt = ((const float4*)ZT)[off];
    const float4 zc = ((const float4*)ZC)[off];
    const float4 zf = ((const float4*)ZF)[off];
    float4 o;
    o.x = aT * zt.x + aC * zc.x + aF * zf.x;
    o.y = aT * zt.y + aC * zc.y + aF * zf.y;
    o.z = aT * zt.z + aC * zc.z + aF * zf.z;
    o.w = aT * zt.w + aC * zc.w + aF * zf.w;
    ((float4*)out)[off] = o;
  }
}

extern "C" void kernel_launch(void* const* d_in, const int* in_sizes, int n_in,
                              void* d_out, int out_size, void* d_ws, size_t ws_size,
                              hipStream_t stream) {
  const float* ZT = (const float*)d_in[0];
  const float* ZC = (const float*)d_in[1];
  const float* ZF = (const float*)d_in[2];
  const float* WT = (const float*)d_in[3];
  const float* bT = (const float*)d_in[4];
  const float* WC = (const float*)d_in[5];
  const float* bC = (const float*)d_in[6];
  const float* WF = (const float*)d_in[7];
  const float* bF = (const float*)d_in[8];
  const float* q  = (const float*)d_in[9];
  float* out = (float*)d_out;

  float* scores = (float*)d_ws;                         // [3][NROWS]
  unsigned* cells = (unsigned*)d_ws + 3 * NROWS;        // [3] max keys
  float* sums = (float*)((unsigned*)d_ws + 3 * NROWS + 3);  // [3]

  // zero the 6 reduction cells (atomicMax identity / sum identity)
  hipMemsetAsync(cells, 0, 6 * sizeof(unsigned), stream);

  dim3 g1((NROWS + RPB - 1) / RPB, 3);
  k_scores<<<g1, 256, 0, stream>>>(ZT, ZC, ZF, WT, bT, WC, bC, WF, bF, q,
                                   scores, cells);

  dim3 g2(64, 3);
  k_redsum<<<g2, 256, 0, stream>>>(scores, cells, sums);

  k_out<<<4096, 256, 0, stream>>>(ZT, ZC, ZF, scores, cells, sums, out);
}

// Round 11
// 732.441 us; speedup vs baseline: 1.4332x; 1.4332x over previous
//
#include <hip/hip_runtime.h>

#define NROWS 100000
#define DDIM 256
#define HDIM 64
#define RPB 256            // rows per block in k_scores (4 waves, 1 row/thread)
#define DCHUNK 16
#define NCHUNK (DDIM / DCHUNK)
#define LDS_STRIDE 20      // 80B rows: 16B-aligned, spreads b128 reads over all banks

__device__ __forceinline__ float fast_tanh(float x) {
  // tanh(x) = 1 - 2/(exp(2x)+1); exact limits at +-inf, ~1ulp elsewhere
  float e = __expf(2.0f * x);
  return 1.0f - 2.0f * __builtin_amdgcn_rcpf(e + 1.0f);
}

// order-preserving float<->uint map for atomicMax over signed floats
__device__ __forceinline__ unsigned enc_key(float f) {
  unsigned b = __float_as_uint(f);
  return (b & 0x80000000u) ? ~b : (b | 0x80000000u);
}
__device__ __forceinline__ float dec_key(unsigned k) {
  unsigned b = (k & 0x80000000u) ? (k & 0x7fffffffu) : ~k;
  return __uint_as_float(b);
}

// cells[0..2] = branch max keys (memset 0 == identity), cells[3..5] = float sums
// Structure: round-2 LDS staging (coalesced global loads, proven low VALU bloat)
// + round-9 (256,1) launch bounds (proven to kill the acc[64] spill: VGPR 56->84).
__global__ __launch_bounds__(256, 1)
void k_scores(const float* __restrict__ ZT, const float* __restrict__ ZC,
              const float* __restrict__ ZF,
              const float* __restrict__ WT, const float* __restrict__ bT,
              const float* __restrict__ WC, const float* __restrict__ bC,
              const float* __restrict__ WF, const float* __restrict__ bF,
              const float* __restrict__ q, float* __restrict__ scores,
              unsigned* __restrict__ cells) {
  __shared__ float zt[RPB][LDS_STRIDE];

  const int br = blockIdx.y;
  const float* __restrict__ Z = (br == 0) ? ZT : (br == 1) ? ZC : ZF;
  const float* __restrict__ W = (br == 0) ? WT : (br == 1) ? WC : WF;
  const float* __restrict__ B = (br == 0) ? bT : (br == 1) ? bC : bF;

  const int tid = threadIdx.x;
  const int row0 = blockIdx.x * RPB;
  const int myrow = row0 + tid;

  float acc[HDIM];
#pragma unroll
  for (int j = 0; j < HDIM; ++j) acc[j] = B[j];            // uniform -> s_load

#pragma unroll 1
  for (int c = 0; c < NCHUNK; ++c) {
    const int d0 = c * DCHUNK;
    __syncthreads();   // protect LDS from previous chunk's readers
    // stage RPB x DCHUNK tile: 1024 float4, 4 per thread, coalesced 64B/row
#pragma unroll
    for (int k = 0; k < 4; ++k) {
      const int f = tid + k * 256;
      const int r = f >> 2, seg = f & 3;
      float4 v = make_float4(0.f, 0.f, 0.f, 0.f);
      const int gr = row0 + r;
      if (gr < NROWS)
        v = *(const float4*)(Z + (size_t)gr * DDIM + d0 + seg * 4);
      *(float4*)(&zt[r][seg * 4]) = v;
    }
    __syncthreads();

    // my row's chunk into registers (4x ds_read_b128; stride-20 rows spread banks)
    float zr[DCHUNK];
#pragma unroll
    for (int k = 0; k < 4; ++k)
      *(float4*)(&zr[k * 4]) = *(const float4*)(&zt[tid][k * 4]);

    // W row is wave-uniform -> s_load + SGPR operand in v_fmac_f32
#pragma unroll
    for (int j = 0; j < HDIM; ++j) {
      const float* __restrict__ Wp = W + j * DDIM + d0;
#pragma unroll
      for (int dd = 0; dd < DCHUNK; ++dd)
        acc[j] = fmaf(Wp[dd], zr[dd], acc[j]);
    }
  }

  float s = 0.f;
#pragma unroll
  for (int j = 0; j < HDIM; ++j) s += q[j] * fast_tanh(acc[j]);

  if (myrow < NROWS) scores[(size_t)br * NROWS + myrow] = s;

  // fused global max: wave reduce -> block reduce -> one atomic per block
  float m = (myrow < NROWS) ? s : -3.4e38f;
#pragma unroll
  for (int off = 32; off > 0; off >>= 1) m = fmaxf(m, __shfl_down(m, off, 64));
  __shared__ float wmax[4];
  if ((tid & 63) == 0) wmax[tid >> 6] = m;
  __syncthreads();
  if (tid == 0) {
    m = fmaxf(fmaxf(wmax[0], wmax[1]), fmaxf(wmax[2], wmax[3]));
    atomicMax(&cells[br], enc_key(m));
  }
}

__global__ __launch_bounds__(256)
void k_redsum(const float* __restrict__ scores, const unsigned* __restrict__ cells,
              float* __restrict__ sums) {
  const int br = blockIdx.y;
  const float mx = dec_key(cells[br]);
  const float* __restrict__ s = scores + (size_t)br * NROWS;
  float a = 0.f;
  for (int i = blockIdx.x * blockDim.x + threadIdx.x; i < NROWS;
       i += gridDim.x * blockDim.x)
    a += __expf(s[i] - mx);
#pragma unroll
  for (int off = 32; off > 0; off >>= 1) a += __shfl_down(a, off, 64);
  __shared__ float wsum[4];
  if ((threadIdx.x & 63) == 0) wsum[threadIdx.x >> 6] = a;
  __syncthreads();
  if (threadIdx.x == 0)
    atomicAdd(&sums[br], wsum[0] + wsum[1] + wsum[2] + wsum[3]);
}

__global__ __launch_bounds__(256)
void k_out(const float* __restrict__ ZT, const float* __restrict__ ZC,
           const float* __restrict__ ZF,
           const float* __restrict__ scores, const unsigned* __restrict__ cells,
           const float* __restrict__ sums, float* __restrict__ out) {
  const float mT = dec_key(cells[0]);
  const float mC = dec_key(cells[1]);
  const float mF = dec_key(cells[2]);
  const float rT = 1.0f / sums[0];
  const float rC = 1.0f / sums[1];
  const float rF = 1.0f / sums[2];

  const long long total4 = (long long)NROWS * (DDIM / 4);
  for (long long g = (long long)blockIdx.x * 256 + threadIdx.x; g < total4;
       g += (long long)gridDim.x * 256) {
    const int row = (int)(g >> 6);   // one wave covers exactly one row
    const float aT = __expf(scores[row] - mT) * rT;
    const float aC = __expf(scores[NROWS + row] - mC) * rC;
    const float aF = __expf(scores[2 * NROWS + row] - mF) * rF;

    const size_t off = (size_t)g;
    const float4 zt = ((const float4*)ZT)[off];
    const float4 zc = ((const float4*)ZC)[off];
    const float4 zf = ((const float4*)ZF)[off];
    float4 o;
    o.x = aT * zt.x + aC * zc.x + aF * zf.x;
    o.y = aT * zt.y + aC * zc.y + aF * zf.y;
    o.z = aT * zt.z + aC * zc.z + aF * zf.z;
    o.w = aT * zt.w + aC * zc.w + aF * zf.w;
    ((float4*)out)[off] = o;
  }
}

extern "C" void kernel_launch(void* const* d_in, const int* in_sizes, int n_in,
                              void* d_out, int out_size, void* d_ws, size_t ws_size,
                              hipStream_t stream) {
  const float* ZT = (const float*)d_in[0];
  const float* ZC = (const float*)d_in[1];
  const float* ZF = (const float*)d_in[2];
  const float* WT = (const float*)d_in[3];
  const float* bT = (const float*)d_in[4];
  const float* WC = (const float*)d_in[5];
  const float* bC = (const float*)d_in[6];
  const float* WF = (const float*)d_in[7];
  const float* bF = (const float*)d_in[8];
  const float* q  = (const float*)d_in[9];
  float* out = (float*)d_out;

  float* scores = (float*)d_ws;                         // [3][NROWS]
  unsigned* cells = (unsigned*)d_ws + 3 * NROWS;        // [3] max keys
  float* sums = (float*)((unsigned*)d_ws + 3 * NROWS + 3);  // [3]

  // zero the 6 reduction cells (atomicMax identity / sum identity)
  hipMemsetAsync(cells, 0, 6 * sizeof(unsigned), stream);

  dim3 g1((NROWS + RPB - 1) / RPB, 3);
  k_scores<<<g1, 256, 0, stream>>>(ZT, ZC, ZF, WT, bT, WC, bC, WF, bF, q,
                                   scores, cells);

  dim3 g2(64, 3);
  k_redsum<<<g2, 256, 0, stream>>>(scores, cells, sums);

  k_out<<<4096, 256, 0, stream>>>(ZT, ZC, ZF, scores, cells, sums, out);
}

// Round 15
// 510.776 us; speedup vs baseline: 2.0551x; 1.4340x over previous
//
#include <hip/hip_runtime.h>

#define NROWS 100000
#define DDIM 256
#define HDIM 64
#define RPB 64             // rows per block: one per lane; 4 waves split H
#define DCHUNK 16
#define NCHUNK (DDIM / DCHUNK)
#define JPW 16             // H-slice per wave (HDIM / 4 waves)
#define LDS_STRIDE 20      // 16 + 4 pad: 16B-aligned, b128 reads cover all banks

__device__ __forceinline__ float fast_tanh(float x) {
  // tanh(x) = 1 - 2/(exp(2x)+1); exact limits at +-inf, ~1ulp elsewhere
  float e = __expf(2.0f * x);
  return 1.0f - 2.0f * __builtin_amdgcn_rcpf(e + 1.0f);
}

// order-preserving float<->uint map for atomicMax over signed floats
__device__ __forceinline__ unsigned enc_key(float f) {
  unsigned b = __float_as_uint(f);
  return (b & 0x80000000u) ? ~b : (b | 0x80000000u);
}
__device__ __forceinline__ float dec_key(unsigned k) {
  unsigned b = (k & 0x80000000u) ? (k & 0x7fffffffu) : ~k;
  return __uint_as_float(b);
}

// cells[0..2] = branch max keys (memset 0 == identity), cells[3..5] = float sums
// Anti-spill structure: 16 accumulators/thread (fits UNDER the compiler's
// measured 52-VGPR preference, so scratch is impossible). Wave w owns
// j in [16w,16w+16); readfirstlane(jbase) restores provable wave-uniformity
// so W/b/q stay s_load + SGPR-operand v_fmac.
__global__ __launch_bounds__(256)
void k_scores(const float* __restrict__ ZT, const float* __restrict__ ZC,
              const float* __restrict__ ZF,
              const float* __restrict__ WT, const float* __restrict__ bT,
              const float* __restrict__ WC, const float* __restrict__ bC,
              const float* __restrict__ WF, const float* __restrict__ bF,
              const float* __restrict__ q, float* __restrict__ scores,
              unsigned* __restrict__ cells) {
  __shared__ float zt[RPB][LDS_STRIDE];     // 5120 B
  __shared__ float partials[4][RPB];        // 1024 B

  const int br = blockIdx.y;
  const float* __restrict__ Z = (br == 0) ? ZT : (br == 1) ? ZC : ZF;
  const float* __restrict__ W = (br == 0) ? WT : (br == 1) ? WC : WF;
  const float* __restrict__ B = (br == 0) ? bT : (br == 1) ? bC : bF;

  const int tid = threadIdx.x;
  const int lane = tid & 63;
  const int wave = tid >> 6;
  const int row0 = blockIdx.x * RPB;
  const int myrow = row0 + lane;
  // wave-uniform j-slice base; readfirstlane makes uniformity provable -> s_load
  const int jbase = __builtin_amdgcn_readfirstlane(wave * JPW);

  float acc[JPW];
#pragma unroll
  for (int j = 0; j < JPW; ++j) acc[j] = B[jbase + j];   // uniform -> s_load

#pragma unroll 1
  for (int c = 0; c < NCHUNK; ++c) {
    const int d0 = c * DCHUNK;
    __syncthreads();   // protect LDS from previous chunk's readers
    // stage 64 rows x 16 floats = 256 float4: thread t -> row t>>2, seg t&3
    {
      const int r = tid >> 2, seg = tid & 3;
      const int gr = row0 + r;
      float4 v = make_float4(0.f, 0.f, 0.f, 0.f);
      if (gr < NROWS)
        v = *(const float4*)(Z + (size_t)gr * DDIM + d0 + seg * 4);
      *(float4*)(&zt[r][seg * 4]) = v;
    }
    __syncthreads();

    // my row's chunk (4x ds_read_b128; stride-20 spreads 8 lanes over 32 banks)
    float zr[DCHUNK];
#pragma unroll
    for (int k = 0; k < 4; ++k)
      *(float4*)(&zr[k * 4]) = *(const float4*)(&zt[lane][k * 4]);

    // W row is provably wave-uniform -> s_load + SGPR operand in v_fmac_f32
#pragma unroll
    for (int j = 0; j < JPW; ++j) {
      const float* __restrict__ Wp = W + (size_t)(jbase + j) * DDIM + d0;
#pragma unroll
      for (int dd = 0; dd < DCHUNK; ++dd)
        acc[j] = fmaf(Wp[dd], zr[dd], acc[j]);
    }
  }

  // per-lane partial score over this wave's 16 j's
  float sw = 0.f;
#pragma unroll
  for (int j = 0; j < JPW; ++j) sw += q[jbase + j] * fast_tanh(acc[j]);

  partials[wave][lane] = sw;
  __syncthreads();

  if (wave == 0) {
    float s = partials[0][lane] + partials[1][lane] +
              partials[2][lane] + partials[3][lane];
    if (myrow < NROWS) scores[(size_t)br * NROWS + myrow] = s;

    // fused global max: wave0 shfl-reduce over its 64 rows -> one atomic/block
    float m = (myrow < NROWS) ? s : -3.4e38f;
#pragma unroll
    for (int off = 32; off > 0; off >>= 1)
      m = fmaxf(m, __shfl_down(m, off, 64));
    if (lane == 0) atomicMax(&cells[br], enc_key(m));
  }
}

__global__ __launch_bounds__(256)
void k_redsum(const float* __restrict__ scores, const unsigned* __restrict__ cells,
              float* __restrict__ sums) {
  const int br = blockIdx.y;
  const float mx = dec_key(cells[br]);
  const float* __restrict__ s = scores + (size_t)br * NROWS;
  float a = 0.f;
  for (int i = blockIdx.x * blockDim.x + threadIdx.x; i < NROWS;
       i += gridDim.x * blockDim.x)
    a += __expf(s[i] - mx);
#pragma unroll
  for (int off = 32; off > 0; off >>= 1) a += __shfl_down(a, off, 64);
  __shared__ float wsum[4];
  if ((threadIdx.x & 63) == 0) wsum[threadIdx.x >> 6] = a;
  __syncthreads();
  if (threadIdx.x == 0)
    atomicAdd(&sums[br], wsum[0] + wsum[1] + wsum[2] + wsum[3]);
}

__global__ __launch_bounds__(256)
void k_out(const float* __restrict__ ZT, const float* __restrict__ ZC,
           const float* __restrict__ ZF,
           const float* __restrict__ scores, const unsigned* __restrict__ cells,
           const float* __restrict__ sums, float* __restrict__ out) {
  const float mT = dec_key(cells[0]);
  const float mC = dec_key(cells[1]);
  const float mF = dec_key(cells[2]);
  const float rT = 1.0f / sums[0];
  const float rC = 1.0f / sums[1];
  const float rF = 1.0f / sums[2];

  const long long total4 = (long long)NROWS * (DDIM / 4);
  for (long long g = (long long)blockIdx.x * 256 + threadIdx.x; g < total4;
       g += (long long)gridDim.x * 256) {
    const int row = (int)(g >> 6);   // one wave covers exactly one row
    const float aT = __expf(scores[row] - mT) * rT;
    const float aC = __expf(scores[NROWS + row] - mC) * rC;
    const float aF = __expf(scores[2 * NROWS + row] - mF) * rF;

    const size_t off = (size_t)g;
    const float4 zt = ((const float4*)ZT)[off];
    const float4 zc = ((const float4*)ZC)[off];
    const float4 zf = ((const float4*)ZF)[off];
    float4 o;
    o.x = aT * zt.x + aC * zc.x + aF * zf.x;
    o.y = aT * zt.y + aC * zc.y + aF * zf.y;
    o.z = aT * zt.z + aC * zc.z + aF * zf.z;
    o.w = aT * zt.w + aC * zc.w + aF * zf.w;
    ((float4*)out)[off] = o;
  }
}

extern "C" void kernel_launch(void* const* d_in, const int* in_sizes, int n_in,
                              void* d_out, int out_size, void* d_ws, size_t ws_size,
                              hipStream_t stream) {
  const float* ZT = (const float*)d_in[0];
  const float* ZC = (const float*)d_in[1];
  const float* ZF = (const float*)d_in[2];
  const float* WT = (const float*)d_in[3];
  const float* bT = (const float*)d_in[4];
  const float* WC = (const float*)d_in[5];
  const float* bC = (const float*)d_in[6];
  const float* WF = (const float*)d_in[7];
  const float* bF = (const float*)d_in[8];
  const float* q  = (const float*)d_in[9];
  float* out = (float*)d_out;

  float* scores = (float*)d_ws;                         // [3][NROWS]
  unsigned* cells = (unsigned*)d_ws + 3 * NROWS;        // [3] max keys
  float* sums = (float*)((unsigned*)d_ws + 3 * NROWS + 3);  // [3]

  // zero the 6 reduction cells (atomicMax identity / sum identity)
  hipMemsetAsync(cells, 0, 6 * sizeof(unsigned), stream);

  dim3 g1((NROWS + RPB - 1) / RPB, 3);
  k_scores<<<g1, 256, 0, stream>>>(ZT, ZC, ZF, WT, bT, WC, bC, WF, bF, q,
                                   scores, cells);

  dim3 g2(64, 3);
  k_redsum<<<g2, 256, 0, stream>>>(scores, cells, sums);

  k_out<<<4096, 256, 0, stream>>>(ZT, ZC, ZF, scores, cells, sums, out);
}